// Round 17
// baseline (115.518 us; speedup 1.0000x reference)
//
#include <hip/hip_runtime.h>
#include <math.h>

typedef unsigned short us;
typedef short s16x8 __attribute__((ext_vector_type(8)));
typedef float f32x4 __attribute__((ext_vector_type(4)));
typedef float f32x16 __attribute__((ext_vector_type(16)));

#define EPSV 1e-5f

static __device__ inline us f2bf(float f) {            // RNE f32->bf16 (prep only)
  union { float f; unsigned u; } v; v.f = f;
  unsigned r = v.u + 0x7fffu + ((v.u >> 16) & 1u);
  return (us)(r >> 16);
}
static __device__ inline unsigned cvtpk(float lo, float hi) {
  unsigned r;
  asm("v_cvt_pk_bf16_f32 %0, %1, %2" : "=v"(r) : "v"(lo), "v"(hi));
  return r;
}
static __device__ inline us f2bf1(float f) { return (us)cvtpk(f, 0.f); }
static __device__ inline float bflo(unsigned u) { return __uint_as_float(u << 16); }
static __device__ inline float bfhi(unsigned u) { return __uint_as_float(u & 0xffff0000u); }

union AU { s16x8 v; us e[8]; };

// ---------------------------------------------------------------- K0: preconvert weights
__global__ __launch_bounds__(256) void prep_weights(
    const float* __restrict__ w1, const float* __restrict__ w2,
    const float* __restrict__ w3, const float* __restrict__ eW,
    const float* __restrict__ oW,
    us* __restrict__ wt1n, us* __restrict__ wt2L, us* __restrict__ wt3L,
    us* __restrict__ ewB, us* __restrict__ owB) {
  const int gtid = blockIdx.x * 256 + threadIdx.x;
  const int G = gridDim.x * 256;
  for (int i = gtid; i < 1536; i += G) {
    const int oc = i / 48, k = i % 48, t = k >> 2, c = k & 3;
    wt1n[i] = (t < 9 && c < 3) ? f2bf(w1[oc * 27 + c * 9 + t]) : (us)0;
  }
  for (int i = gtid; i < 11520; i += G) {
    const int row = i / 40, col = i % 40;
    const int tap = row >> 5, oc = row & 31;
    wt2L[i] = (col < 32) ? f2bf(w2[oc * 288 + col * 9 + tap]) : (us)0;
    wt3L[i] = (col < 32) ? f2bf(w3[oc * 288 + col * 9 + tap]) : (us)0;
  }
  for (int i = gtid; i < 49152; i += G) ewB[i] = f2bf(eW[i]);
  for (int i = gtid; i < 14336; i += G) {
    const int cls = i >> 7;
    owB[i] = (cls < 100) ? f2bf(oW[cls * 128 + (i & 127)]) : (us)0;
  }
}

// ---------------------------------------------------------------- finalize: partials[ch][2048] -> {scale, shift}
__global__ __launch_bounds__(256) void finalize_stats(
    const float* __restrict__ part, const float* __restrict__ g,
    const float* __restrict__ bb, float cnt, float* __restrict__ stats) {
  __shared__ float redS[256], redQ[256];
  const int ch = blockIdx.x, tid = threadIdx.x;
  const float* ps = part + (size_t)ch * 2048;
  const float* pq = part + (size_t)(32 + ch) * 2048;
  float s = 0.f, q = 0.f;
  for (int i = tid; i < 2048; i += 256) { s += ps[i]; q += pq[i]; }
  redS[tid] = s; redQ[tid] = q;
  __syncthreads();
  for (int off = 128; off; off >>= 1) {
    if (tid < off) { redS[tid] += redS[tid + off]; redQ[tid] += redQ[tid + off]; }
    __syncthreads();
  }
  if (tid == 0) {
    const float mean = redS[0] / cnt;
    const float var = redQ[0] / cnt - mean * mean;
    const float sc = g[ch] * rsqrtf(var + EPSV);
    stats[ch] = sc;
    stats[32 + ch] = bb[ch] - mean * sc;
  }
}

// conv1 helper: stage x c-minor [32][32][4] bf16 (+zero pad at 4096)
static __device__ inline void stage_x_cminor(const float* xp, us* xsb4, int tid) {
#pragma unroll
  for (int k = 0; k < 4; ++k) {
    const int p = tid + k * 256;
    const unsigned lo = cvtpk(xp[p], xp[1024 + p]);
    const unsigned hi = cvtpk(xp[2048 + p], 0.f);
    *(uint2*)&xsb4[p * 4] = make_uint2(lo, hi);
  }
  if (tid < 16) *(uint4*)&xsb4[4096 + tid * 8] = make_uint4(0, 0, 0, 0);
}

// build conv1 permuted-row offset table (u16 element-offsets), entries 0..927
static __device__ inline void build_tbl1(us* tbl, int tid) {
  for (int i = tid; i < 928; i += 256) {
    us v = 0;
    if (i < 900) {
      const int w = i >> 2, e = i & 3;
      v = (us)((((2 * (w / 15) + (e >> 1)) * 32 + 2 * (w % 15) + (e & 1))) * 4);
    }
    tbl[i] = v;
  }
}

// tap -> xsb4 element offset (taps >= 9 -> zero pad region)
static __device__ inline int tapoff(int t) {
  return (t < 9) ? (((t / 3) * 32 + t % 3) * 4) : 4096;
}

// ---------------------------------------------------------------- K1: conv1 stats (32x32x16 MFMA, tap-packed K=48)
__global__ __launch_bounds__(256, 4) void conv1_stats(
    const float* __restrict__ x, const us* __restrict__ wt1n,
    const float* __restrict__ cb, float* __restrict__ part1) {
  __shared__ __align__(16) us xsb4[4224];
  __shared__ us tbl1[928];
  __shared__ float csum[32], css[32];
  const int n = blockIdx.x, tid = threadIdx.x;
  const int wave = tid >> 6, lane = tid & 63, oc = lane & 31, hi = lane >> 5;
  stage_x_cminor(x + (size_t)n * 3072, xsb4, tid);
  build_tbl1(tbl1, tid);
  if (tid < 32) { csum[tid] = 0.f; css[tid] = 0.f; }
  __syncthreads();
  int tA[3], tB[3];
#pragma unroll
  for (int kk = 0; kk < 3; ++kk) {
    tA[kk] = tapoff(4 * kk + 2 * hi);
    tB[kk] = tapoff(4 * kk + 2 * hi + 1);
  }
  s16x8 wb[3];
#pragma unroll
  for (int kk = 0; kk < 3; ++kk)
    wb[kk] = *(const s16x8*)&wt1n[oc * 48 + kk * 16 + hi * 8];
  const float bias = cb[oc];
  float s = 0.f, ss = 0.f;
  for (int mt = wave; mt < 29; mt += 4) {
    const int boff = tbl1[mt * 32 + (lane & 31)];
    f32x16 acc;
#pragma unroll
    for (int r = 0; r < 16; ++r) acc[r] = bias;
#pragma unroll
    for (int kk = 0; kk < 3; ++kk) {
      AU a;
      *(uint2*)&a.e[0] = *(const uint2*)&xsb4[boff + tA[kk]];
      *(uint2*)&a.e[4] = *(const uint2*)&xsb4[boff + tB[kk]];
      acc = __builtin_amdgcn_mfma_f32_32x32x16_bf16(a.v, wb[kk], acc, 0, 0, 0);
    }
    if (mt < 28) {                            // full tile: rows <= 895 < 900
#pragma unroll
      for (int reg = 0; reg < 16; ++reg) { s += acc[reg]; ss += acc[reg] * acc[reg]; }
    } else {                                  // tail tile 28: rows 896..927
#pragma unroll
      for (int reg = 0; reg < 16; ++reg) {
        const int row = 896 + (reg & 3) + 8 * (reg >> 2) + 4 * hi;
        if (row < 900) { s += acc[reg]; ss += acc[reg] * acc[reg]; }
      }
    }
  }
  s += __shfl_down(s, 32); ss += __shfl_down(ss, 32);
  if (lane < 32) { atomicAdd(&csum[oc], s); atomicAdd(&css[oc], ss); }
  __syncthreads();
  if (tid < 32) {
    part1[tid * 2048 + n] = csum[tid];
    part1[(32 + tid) * 2048 + n] = css[tid];
  }
}

// ---------------------------------------------------------------- K2: conv1 apply (32x32) -> p1 (LDS) + conv2 (32x32) -> y2s + part2
__global__ __launch_bounds__(256, 4) void conv1_apply_conv2_stats(
    const float* __restrict__ x, const us* __restrict__ wt1n,
    const float* __restrict__ cb1, const float* __restrict__ stats1,
    const us* __restrict__ wt2L, const float* __restrict__ cb2,
    float* __restrict__ part2, us* __restrict__ y2s) {
  __shared__ __align__(16) us xsb4[4224];
  __shared__ __align__(16) us p1b[9000];      // [225][40]
  __shared__ us tbl1[928];
  __shared__ us tbl2[192];
  __shared__ float scS[32], shS[32], csum[32], css[32];
  const int n = blockIdx.x, tid = threadIdx.x;
  const int wave = tid >> 6, lane = tid & 63, oc = lane & 31, hi = lane >> 5;
  stage_x_cminor(x + (size_t)n * 3072, xsb4, tid);
  build_tbl1(tbl1, tid);
  if (tid < 192) {
    us v = 0;
    const int q = tid;
    if (q < 144) {
      const int w = q >> 2, e = q & 3;
      v = (us)((2 * (w / 6) + (e >> 1)) * 15 + 2 * (w % 6) + (e & 1));
    } else if (q < 169) {
      const int r = q - 144;
      v = (us)((r < 13) ? (12 * 15 + r) : ((r - 13) * 15 + 12));
    }
    tbl2[tid] = v;
  }
  if (tid < 32) {
    scS[tid] = stats1[tid]; shS[tid] = stats1[32 + tid];
    csum[tid] = 0.f; css[tid] = 0.f;
  }
  __syncthreads();
  // ---- conv1 apply + bn1+relu+pool1 -> p1b
  {
    int tA[3], tB[3];
#pragma unroll
    for (int kk = 0; kk < 3; ++kk) {
      tA[kk] = tapoff(4 * kk + 2 * hi);
      tB[kk] = tapoff(4 * kk + 2 * hi + 1);
    }
    s16x8 wb[3];
#pragma unroll
    for (int kk = 0; kk < 3; ++kk)
      wb[kk] = *(const s16x8*)&wt1n[oc * 48 + kk * 16 + hi * 8];
    const float bias = cb1[oc];
    const float sc = scS[oc], sh = shS[oc];
    for (int mt = wave; mt < 29; mt += 4) {
      const int boff = tbl1[mt * 32 + (lane & 31)];
      f32x16 acc;
#pragma unroll
      for (int r = 0; r < 16; ++r) acc[r] = bias;
#pragma unroll
      for (int kk = 0; kk < 3; ++kk) {
        AU a;
        *(uint2*)&a.e[0] = *(const uint2*)&xsb4[boff + tA[kk]];
        *(uint2*)&a.e[4] = *(const uint2*)&xsb4[boff + tB[kk]];
        acc = __builtin_amdgcn_mfma_f32_32x32x16_bf16(a.v, wb[kk], acc, 0, 0, 0);
      }
      if (mt < 28) {                          // all 4 windows valid (w <= 223)
#pragma unroll
        for (int q = 0; q < 4; ++q) {
          const int w = mt * 8 + 2 * q + hi;
          float p = 0.f;
#pragma unroll
          for (int r = 0; r < 4; ++r) p += fmaxf(acc[q * 4 + r] * sc + sh, 0.f);
          p1b[w * 40 + oc] = f2bf1(p * 0.25f);
        }
      } else {                                // tail: w 224..231, only 224 valid
#pragma unroll
        for (int q = 0; q < 4; ++q) {
          const int w = 224 + 2 * q + hi;
          if (w < 225) {
            float p = 0.f;
#pragma unroll
            for (int r = 0; r < 4; ++r) p += fmaxf(acc[q * 4 + r] * sc + sh, 0.f);
            p1b[w * 40 + oc] = f2bf1(p * 0.25f);
          }
        }
      }
    }
  }
  __syncthreads();
  // ---- conv2 (6 tiles of 32 permuted rows) -> y2s + stats
  {
    const float bias2 = cb2[oc];
    float s = 0.f, ss = 0.f;
    for (int mt2 = wave; mt2 < 6; mt2 += 4) {
      const int inb = tbl2[mt2 * 32 + (lane & 31)];
      f32x16 acc;
#pragma unroll
      for (int r = 0; r < 16; ++r) acc[r] = bias2;
#pragma unroll
      for (int tap = 0; tap < 9; ++tap) {
        const int ki = tap / 3, kj = tap % 3;
#pragma unroll
        for (int kk = 0; kk < 2; ++kk) {
          const s16x8 a = *(const s16x8*)&p1b[(inb + ki * 15 + kj) * 40 + kk * 16 + hi * 8];
          const s16x8 b = *(const s16x8*)&wt2L[(tap * 32 + oc) * 40 + kk * 16 + hi * 8];
          acc = __builtin_amdgcn_mfma_f32_32x32x16_bf16(a, b, acc, 0, 0, 0);
        }
      }
      if (mt2 < 4) {                          // stores all valid (w <= 31)
#pragma unroll
        for (int q = 0; q < 4; ++q) {
          const int wloc = mt2 * 8 + 2 * q + hi;
          uint2 pk;
          pk.x = cvtpk(acc[q * 4 + 0], acc[q * 4 + 1]);
          pk.y = cvtpk(acc[q * 4 + 2], acc[q * 4 + 3]);
          *(uint2*)(y2s + (((size_t)n * 36 + wloc) * 32 + oc) * 4) = pk;
        }
      } else {
#pragma unroll
        for (int q = 0; q < 4; ++q) {
          const int wloc = mt2 * 8 + 2 * q + hi;
          if (wloc < 36) {
            uint2 pk;
            pk.x = cvtpk(acc[q * 4 + 0], acc[q * 4 + 1]);
            pk.y = cvtpk(acc[q * 4 + 2], acc[q * 4 + 3]);
            *(uint2*)(y2s + (((size_t)n * 36 + wloc) * 32 + oc) * 4) = pk;
          }
        }
      }
      if (mt2 < 5) {                          // stats rows all valid (<=159)
#pragma unroll
        for (int reg = 0; reg < 16; ++reg) { s += acc[reg]; ss += acc[reg] * acc[reg]; }
      } else {                                // tile 5: rows 160..191, valid <169
#pragma unroll
        for (int reg = 0; reg < 16; ++reg) {
          const int row = 160 + (reg & 3) + 8 * (reg >> 2) + 4 * hi;
          if (row < 169) { s += acc[reg]; ss += acc[reg] * acc[reg]; }
        }
      }
    }
    s += __shfl_down(s, 32); ss += __shfl_down(ss, 32);
    if (lane < 32) { atomicAdd(&csum[oc], s); atomicAdd(&css[oc], ss); }
  }
  __syncthreads();
  if (tid < 32) {
    part2[tid * 2048 + n] = csum[tid];
    part2[(32 + tid) * 2048 + n] = css[tid];
  }
}

// ---------------------------------------------------------------- K3: bnpool2 (from y2s) -> p2 + conv3 partials (8 samples/block)
__global__ __launch_bounds__(256) void bnpool2_conv3_stats(
    const us* __restrict__ y2s, const float* __restrict__ stats2,
    const us* __restrict__ wt3L, const float* __restrict__ cb3,
    float* __restrict__ part3, us* __restrict__ p2g) {
  __shared__ __align__(16) us p2L[11520];      // [8][36][40]
  __shared__ float scS[32], shS[32], csum[32], css[32];
  const int n0 = blockIdx.x * 8, tid = threadIdx.x;
  const int wave = tid >> 6, lane = tid & 63, row16 = lane & 15, kg = lane >> 4;
  if (tid < 32) {
    scS[tid] = stats2[tid]; shS[tid] = stats2[32 + tid];
    csum[tid] = 0.f; css[tid] = 0.f;
  }
  __syncthreads();
#pragma unroll
  for (int it = 0; it < 36; ++it) {
    const int i = tid + it * 256;
    const int c = i & 31, w = (i >> 5) % 36, s = i / 1152;
    const uint2 v = *(const uint2*)(y2s + (((size_t)(n0 + s) * 36 + w) * 32 + c) * 4);
    const float sc = scS[c], sh = shS[c];
    const float p = fmaxf(bflo(v.x) * sc + sh, 0.f) + fmaxf(bfhi(v.x) * sc + sh, 0.f) +
                    fmaxf(bflo(v.y) * sc + sh, 0.f) + fmaxf(bfhi(v.y) * sc + sh, 0.f);
    const us pb = f2bf1(p * 0.25f);
    p2L[(s * 36 + w) * 40 + c] = pb;
    p2g[((size_t)(n0 + s) * 36 + w) * 32 + c] = pb;
  }
  __syncthreads();
  const int inb3 = (row16 >> 2) * 6 + (row16 & 3);
  const float b30 = cb3[row16], b31 = cb3[16 + row16];
  float s0 = 0.f, ss0 = 0.f, s1 = 0.f, ss1 = 0.f;
#pragma unroll
  for (int si = 0; si < 2; ++si) {
    const int s = wave * 2 + si;
    f32x4 a0 = {b30, b30, b30, b30};
    f32x4 a1 = {b31, b31, b31, b31};
#pragma unroll
    for (int tap = 0; tap < 9; ++tap) {
      const int ki = tap / 3, kj = tap % 3;
      const s16x8 wf0 = *(const s16x8*)&wt3L[(tap * 32 + row16) * 40 + kg * 8];
      const s16x8 wf1 = *(const s16x8*)&wt3L[(tap * 32 + 16 + row16) * 40 + kg * 8];
      const s16x8 a = *(const s16x8*)&p2L[(s * 36 + inb3 + ki * 6 + kj) * 40 + kg * 8];
      a0 = __builtin_amdgcn_mfma_f32_16x16x32_bf16(a, wf0, a0, 0, 0, 0);
      a1 = __builtin_amdgcn_mfma_f32_16x16x32_bf16(a, wf1, a1, 0, 0, 0);
    }
#pragma unroll
    for (int r = 0; r < 4; ++r) {
      s0 += a0[r]; ss0 += a0[r] * a0[r];
      s1 += a1[r]; ss1 += a1[r] * a1[r];
    }
  }
  s0 += __shfl_down(s0, 32); s0 += __shfl_down(s0, 16);
  ss0 += __shfl_down(ss0, 32); ss0 += __shfl_down(ss0, 16);
  s1 += __shfl_down(s1, 32); s1 += __shfl_down(s1, 16);
  ss1 += __shfl_down(ss1, 32); ss1 += __shfl_down(ss1, 16);
  if (lane < 16) {
    atomicAdd(&csum[row16], s0); atomicAdd(&css[row16], ss0);
    atomicAdd(&csum[16 + row16], s1); atomicAdd(&css[16 + row16], ss1);
  }
  __syncthreads();
  if (tid < 32) {
    part3[tid * 2048 + blockIdx.x] = csum[tid];
    part3[(32 + tid) * 2048 + blockIdx.x] = css[tid];
  }
}

// ---------------------------------------------------------------- finalize for K3's 256-block partials
__global__ __launch_bounds__(256) void finalize_stats256(
    const float* __restrict__ part, const float* __restrict__ g,
    const float* __restrict__ bb, float cnt, float* __restrict__ stats) {
  __shared__ float redS[256], redQ[256];
  const int ch = blockIdx.x, tid = threadIdx.x;
  const float* ps = part + (size_t)ch * 2048;
  const float* pq = part + (size_t)(32 + ch) * 2048;
  redS[tid] = ps[tid]; redQ[tid] = pq[tid];
  __syncthreads();
  for (int off = 128; off; off >>= 1) {
    if (tid < off) { redS[tid] += redS[tid + off]; redQ[tid] += redQ[tid + off]; }
    __syncthreads();
  }
  if (tid == 0) {
    const float mean = redS[0] / cnt;
    const float var = redQ[0] / cnt - mean * mean;
    const float sc = g[ch] * rsqrtf(var + EPSV);
    stats[ch] = sc;
    stats[32 + ch] = bb[ch] - mean * sc;
  }
}

// ---------------------------------------------------------------- K4: conv3 apply + routed MLP fused (8 samples/block, 1 wave)
__global__ __launch_bounds__(64) void conv3_apply_mlp(
    const us* __restrict__ p2g, const us* __restrict__ wt3L,
    const float* __restrict__ cb3, const float* __restrict__ stats3,
    const float* __restrict__ traj,
    const us* __restrict__ ewB, const float* __restrict__ eb,
    const us* __restrict__ owB, const float* __restrict__ ob,
    float* __restrict__ out) {
  __shared__ __align__(16) us p2L[11520];      // [8][36][40]
  __shared__ float h0a[1024];                  // [8][128]
  __shared__ __align__(16) us ht[16 * 136];
  __shared__ float scS[32], shS[32], ebl[384], obl[112];
  const int lane = threadIdx.x, row16 = lane & 15, kg = lane >> 4;
  const int n0 = blockIdx.x * 8, rbase = blockIdx.x * 16;
  for (int i = lane; i < 1152; i += 64) {
    const int s = i / 144, ci = i - s * 144;
    const uint4 v = ((const uint4*)(p2g + (size_t)n0 * 1152))[i];
    *(uint4*)&p2L[(s * 36 + (ci >> 2)) * 40 + (ci & 3) * 8] = v;
  }
  if (lane < 32) { scS[lane] = stats3[lane]; shS[lane] = stats3[32 + lane]; }
  for (int i = lane; i < 384; i += 64) ebl[i] = eb[i];
  for (int i = lane; i < 112; i += 64) obl[i] = (i < 100) ? ob[i] : 0.f;
  __syncthreads();
  const int wA = row16 >> 2, eA = row16 & 3;
  const int inb3 = (2 * (wA >> 1) + (eA >> 1)) * 6 + 2 * (wA & 1) + (eA & 1);
  const float b30 = cb3[row16], b31 = cb3[16 + row16];
  const float sc0 = scS[row16], sh0 = shS[row16];
  const float sc1 = scS[16 + row16], sh1 = shS[16 + row16];
#pragma unroll
  for (int s = 0; s < 8; ++s) {
    f32x4 a0 = {b30, b30, b30, b30};
    f32x4 a1 = {b31, b31, b31, b31};
#pragma unroll
    for (int tap = 0; tap < 9; ++tap) {
      const int ki = tap / 3, kj = tap % 3;
      const s16x8 wf0 = *(const s16x8*)&wt3L[(tap * 32 + row16) * 40 + kg * 8];
      const s16x8 wf1 = *(const s16x8*)&wt3L[(tap * 32 + 16 + row16) * 40 + kg * 8];
      const s16x8 a = *(const s16x8*)&p2L[(s * 36 + inb3 + ki * 6 + kj) * 40 + kg * 8];
      a0 = __builtin_amdgcn_mfma_f32_16x16x32_bf16(a, wf0, a0, 0, 0, 0);
      a1 = __builtin_amdgcn_mfma_f32_16x16x32_bf16(a, wf1, a1, 0, 0, 0);
    }
    float p0 = 0.f, p1v = 0.f;
#pragma unroll
    for (int r = 0; r < 4; ++r) {
      p0 += fmaxf(a0[r] * sc0 + sh0, 0.f);
      p1v += fmaxf(a1[r] * sc1 + sh1, 0.f);
    }
    h0a[s * 128 + row16 * 4 + kg] = p0 * 0.25f;
    h0a[s * 128 + (16 + row16) * 4 + kg] = p1v * 0.25f;
  }
  __syncthreads();
#pragma unroll
  for (int q = 0; q < 4; ++q) {
    const int u = lane + q * 64;
    const int lr = u >> 4, d8 = (u & 15) * 8;
    const float* hp = &h0a[(lr >> 1) * 128 + d8];
    uint4 p;
    p.x = cvtpk(hp[0], hp[1]); p.y = cvtpk(hp[2], hp[3]);
    p.z = cvtpk(hp[4], hp[5]); p.w = cvtpk(hp[6], hp[7]);
    *(uint4*)&ht[lr * 136 + d8] = p;
  }
  float accv[8][4];
#pragma unroll
  for (int ct = 0; ct < 8; ++ct)
#pragma unroll
    for (int r = 0; r < 4; ++r)
      accv[ct][r] = h0a[((kg * 4 + r) >> 1) * 128 + ct * 16 + row16];
  __syncthreads();
  for (int d = 0; d < 3; ++d) {
    int sel[4];
#pragma unroll
    for (int r = 0; r < 4; ++r) {
      const int rowg = rbase + kg * 4 + r;
      const float4 t4 = *(const float4*)(traj + d * 16384 + rowg * 4);
      int s = 0; float mx = t4.x;
      if (t4.y > mx) { mx = t4.y; s = 1; }
      if (t4.z > mx) { mx = t4.z; s = 2; }
      if (t4.w > mx) { mx = t4.w; s = 3; }
      sel[r] = s;
    }
    s16x8 a[4];
#pragma unroll
    for (int kc = 0; kc < 4; ++kc)
      a[kc] = *(const s16x8*)&ht[row16 * 136 + kc * 32 + kg * 8];
    float newacc[8][4];
#pragma unroll
    for (int ct = 0; ct < 8; ++ct)
#pragma unroll
      for (int r = 0; r < 4; ++r)
        newacc[ct][r] = (sel[r] == 3) ? accv[ct][r] : 0.f;
#pragma unroll
    for (int e = 0; e < 3; ++e) {
#pragma unroll
      for (int ct = 0; ct < 8; ++ct) {
        f32x4 t = {0.f, 0.f, 0.f, 0.f};
#pragma unroll
        for (int kc = 0; kc < 4; ++kc) {
          const s16x8 b = *(const s16x8*)&ewB[(e * 128 + ct * 16 + row16) * 128 + kc * 32 + kg * 8];
          t = __builtin_amdgcn_mfma_f32_16x16x32_bf16(a[kc], b, t, 0, 0, 0);
        }
        const float bias = ebl[e * 128 + ct * 16 + row16];
#pragma unroll
        for (int r = 0; r < 4; ++r)
          if (sel[r] == e) newacc[ct][r] = t[r] + bias;
      }
    }
#pragma unroll
    for (int ct = 0; ct < 8; ++ct)
#pragma unroll
      for (int r = 0; r < 4; ++r) {
        float v = newacc[ct][r];
        if (d < 2) v = fmaxf(v, 0.f);
        accv[ct][r] = v;
        ht[(kg * 4 + r) * 136 + ct * 16 + row16] = f2bf1(v);
      }
  }
  s16x8 a[4];
#pragma unroll
  for (int kc = 0; kc < 4; ++kc)
    a[kc] = *(const s16x8*)&ht[row16 * 136 + kc * 32 + kg * 8];
  float preds[7][4];
#pragma unroll
  for (int ct = 0; ct < 7; ++ct) {
    f32x4 t = {0.f, 0.f, 0.f, 0.f};
#pragma unroll
    for (int kc = 0; kc < 4; ++kc) {
      const s16x8 b = *(const s16x8*)&owB[(ct * 16 + row16) * 128 + kc * 32 + kg * 8];
      t = __builtin_amdgcn_mfma_f32_16x16x32_bf16(a[kc], b, t, 0, 0, 0);
    }
    const float bias = obl[ct * 16 + row16];
#pragma unroll
    for (int r = 0; r < 4; ++r) preds[ct][r] = t[r] + bias;
  }
  const bool v6 = (96 + row16) < 100;
#pragma unroll
  for (int r = 0; r < 4; ++r) {
    float mx = -INFINITY;
#pragma unroll
    for (int ct = 0; ct < 7; ++ct)
      if (ct < 6 || v6) mx = fmaxf(mx, preds[ct][r]);
    mx = fmaxf(mx, __shfl_xor(mx, 1)); mx = fmaxf(mx, __shfl_xor(mx, 2));
    mx = fmaxf(mx, __shfl_xor(mx, 4)); mx = fmaxf(mx, __shfl_xor(mx, 8));
    float s = 0.f;
#pragma unroll
    for (int ct = 0; ct < 7; ++ct)
      if (ct < 6 || v6) s += expf(preds[ct][r] - mx);
    s += __shfl_xor(s, 1); s += __shfl_xor(s, 2);
    s += __shfl_xor(s, 4); s += __shfl_xor(s, 8);
    const float lg = mx + logf(s);
    const int rowg = rbase + kg * 4 + r;
#pragma unroll
    for (int ct = 0; ct < 7; ++ct)
      if (ct < 6 || v6) out[(size_t)rowg * 100 + ct * 16 + row16] = preds[ct][r] - lg;
  }
}

// ---------------------------------------------------------------- launch
extern "C" void kernel_launch(void* const* d_in, const int* in_sizes, int n_in,
                              void* d_out, int out_size, void* d_ws, size_t ws_size,
                              hipStream_t stream) {
  const float* x     = (const float*)d_in[0];
  const float* traj  = (const float*)d_in[1];
  const float* score = (const float*)d_in[2];
  const float* cw1 = (const float*)d_in[3];
  const float* cb1 = (const float*)d_in[4];
  const float* g1  = (const float*)d_in[5];
  const float* bb1 = (const float*)d_in[6];
  const float* cw2 = (const float*)d_in[7];
  const float* cb2 = (const float*)d_in[8];
  const float* g2  = (const float*)d_in[9];
  const float* bb2 = (const float*)d_in[10];
  const float* cw3 = (const float*)d_in[11];
  const float* cb3 = (const float*)d_in[12];
  const float* g3  = (const float*)d_in[13];
  const float* bb3 = (const float*)d_in[14];
  const float* eW  = (const float*)d_in[15];
  const float* eb  = (const float*)d_in[16];
  const float* oW  = (const float*)d_in[17];
  const float* ob  = (const float*)d_in[18];
  float* out = (float*)d_out;

  char* ws = (char*)d_ws;
  float* stats1 = (float*)ws;
  float* stats2 = (float*)(ws + 256);
  float* stats3 = (float*)(ws + 512);
  us* wt1n  = (us*)(ws + 1024);
  us* wt2L  = (us*)(ws + 8192);
  us* wt3L  = (us*)(ws + 8192 + 23040);
  us* ewB   = (us*)(ws + 65536);
  us* owB   = (us*)(ws + 65536 + 98304);
  us* y2s   = (us*)(ws + 262144);                // bf16 [2048][36][32][4]
  us* p2g   = (us*)(ws + 262144 + 18874368);     // bf16 [2048][36][32]
  char* pbase = ws + 262144 + 18874368 + 4718592;
  float* part1 = (float*)pbase;
  float* part2 = (float*)(pbase + 524288);
  float* part3 = (float*)(pbase + 1048576);

  prep_weights<<<64, 256, 0, stream>>>(cw1, cw2, cw3, eW, oW,
                                       wt1n, wt2L, wt3L, ewB, owB);
  conv1_stats<<<2048, 256, 0, stream>>>(x, wt1n, cb1, part1);
  finalize_stats<<<32, 256, 0, stream>>>(part1, g1, bb1, 2048.f * 900.f, stats1);
  conv1_apply_conv2_stats<<<2048, 256, 0, stream>>>(x, wt1n, cb1, stats1,
                                                    wt2L, cb2, part2, y2s);
  finalize_stats<<<32, 256, 0, stream>>>(part2, g2, bb2, 2048.f * 169.f, stats2);
  bnpool2_conv3_stats<<<256, 256, 0, stream>>>(y2s, stats2, wt3L, cb3, part3, p2g);
  finalize_stats256<<<32, 256, 0, stream>>>(part3, g3, bb3, 2048.f * 16.f, stats3);
  conv3_apply_mlp<<<256, 64, 0, stream>>>(p2g, wt3L, cb3, stats3, traj,
                                          ewB, eb, owB, ob, out);
  hipMemcpyAsync(out + 409600, score, 4096 * sizeof(float),
                 hipMemcpyDeviceToDevice, stream);
}

// Round 19
// 97.848 us; speedup vs baseline: 1.1806x; 1.1806x over previous
//
#include <hip/hip_runtime.h>
#include <math.h>

typedef unsigned short us;
typedef short s16x8 __attribute__((ext_vector_type(8)));
typedef float f32x4 __attribute__((ext_vector_type(4)));
typedef float f32x16 __attribute__((ext_vector_type(16)));

#define EPSV 1e-5f

static __device__ inline us f2bf(float f) {            // RNE f32->bf16 (prep only)
  union { float f; unsigned u; } v; v.f = f;
  unsigned r = v.u + 0x7fffu + ((v.u >> 16) & 1u);
  return (us)(r >> 16);
}
static __device__ inline unsigned cvtpk(float lo, float hi) {
  unsigned r;
  asm("v_cvt_pk_bf16_f32 %0, %1, %2" : "=v"(r) : "v"(lo), "v"(hi));
  return r;
}
static __device__ inline us f2bf1(float f) { return (us)cvtpk(f, 0.f); }
static __device__ inline float bflo(unsigned u) { return __uint_as_float(u << 16); }
static __device__ inline float bfhi(unsigned u) { return __uint_as_float(u & 0xffff0000u); }

union AU { s16x8 v; us e[8]; };

// ---------------------------------------------------------------- K0: preconvert weights
// wt1n[32oc][48k]: k = tap*4 + c (tap<9, c<3 real; else 0)
// wt2L/wt3L[(tap*32+oc)][40]; ewB[3*128*128]; owB[112*128]
__global__ __launch_bounds__(256) void prep_weights(
    const float* __restrict__ w1, const float* __restrict__ w2,
    const float* __restrict__ w3, const float* __restrict__ eW,
    const float* __restrict__ oW,
    us* __restrict__ wt1n, us* __restrict__ wt2L, us* __restrict__ wt3L,
    us* __restrict__ ewB, us* __restrict__ owB) {
  const int gtid = blockIdx.x * 256 + threadIdx.x;
  const int G = gridDim.x * 256;
  for (int i = gtid; i < 1536; i += G) {
    const int oc = i / 48, k = i % 48, t = k >> 2, c = k & 3;
    wt1n[i] = (t < 9 && c < 3) ? f2bf(w1[oc * 27 + c * 9 + t]) : (us)0;
  }
  for (int i = gtid; i < 11520; i += G) {
    const int row = i / 40, col = i % 40;
    const int tap = row >> 5, oc = row & 31;
    wt2L[i] = (col < 32) ? f2bf(w2[oc * 288 + col * 9 + tap]) : (us)0;
    wt3L[i] = (col < 32) ? f2bf(w3[oc * 288 + col * 9 + tap]) : (us)0;
  }
  for (int i = gtid; i < 49152; i += G) ewB[i] = f2bf(eW[i]);
  for (int i = gtid; i < 14336; i += G) {
    const int cls = i >> 7;
    owB[i] = (cls < 100) ? f2bf(oW[cls * 128 + (i & 127)]) : (us)0;
  }
}

// ---------------------------------------------------------------- finalize: partials[ch][2048] -> {scale, shift}
__global__ __launch_bounds__(256) void finalize_stats(
    const float* __restrict__ part, const float* __restrict__ g,
    const float* __restrict__ bb, float cnt, float* __restrict__ stats) {
  __shared__ float redS[256], redQ[256];
  const int ch = blockIdx.x, tid = threadIdx.x;
  const float* ps = part + (size_t)ch * 2048;
  const float* pq = part + (size_t)(32 + ch) * 2048;
  float s = 0.f, q = 0.f;
  for (int i = tid; i < 2048; i += 256) { s += ps[i]; q += pq[i]; }
  redS[tid] = s; redQ[tid] = q;
  __syncthreads();
  for (int off = 128; off; off >>= 1) {
    if (tid < off) { redS[tid] += redS[tid + off]; redQ[tid] += redQ[tid + off]; }
    __syncthreads();
  }
  if (tid == 0) {
    const float mean = redS[0] / cnt;
    const float var = redQ[0] / cnt - mean * mean;
    const float sc = g[ch] * rsqrtf(var + EPSV);
    stats[ch] = sc;
    stats[32 + ch] = bb[ch] - mean * sc;
  }
}

// conv1 helper: stage x c-minor [32][32][4] bf16
static __device__ inline void stage_x_cminor(const float* xp, us* xsb4, int tid) {
#pragma unroll
  for (int k = 0; k < 4; ++k) {
    const int p = tid + k * 256;
    const unsigned lo = cvtpk(xp[p], xp[1024 + p]);
    const unsigned hi = cvtpk(xp[2048 + p], 0.f);
    *(uint2*)&xsb4[p * 4] = make_uint2(lo, hi);
  }
}

// build conv1 permuted-row offset table (u16 element-offsets), entries 0..927
static __device__ inline void build_tbl1(us* tbl, int tid) {
  for (int i = tid; i < 928; i += 256) {
    us v = 0;
    if (i < 900) {
      const int w = i >> 2, e = i & 3;
      v = (us)((((2 * (w / 15) + (e >> 1)) * 32 + 2 * (w % 15) + (e & 1))) * 4);
    }
    tbl[i] = v;
  }
}

// tap (0..8 only) -> xsb4 element offset
static __device__ inline int tapoff(int t) {
  return ((t / 3) * 32 + t % 3) * 4;
}

// ---------------------------------------------------------------- K1: conv1 stats (32x32x16 MFMA, tap-packed K=48)
__global__ __launch_bounds__(256, 4) void conv1_stats(
    const float* __restrict__ x, const us* __restrict__ wt1n,
    const float* __restrict__ cb, float* __restrict__ part1) {
  __shared__ __align__(16) us xsb4[4096];
  __shared__ us tbl1[928];
  __shared__ float csum[32], css[32];
  const int n = blockIdx.x, tid = threadIdx.x;
  const int wave = tid >> 6, lane = tid & 63, oc = lane & 31, hi = lane >> 5;
  stage_x_cminor(x + (size_t)n * 3072, xsb4, tid);
  build_tbl1(tbl1, tid);
  if (tid < 32) { csum[tid] = 0.f; css[tid] = 0.f; }
  __syncthreads();
  // kk=0: taps {0,1}(hi=0)/{2,3}(hi=1); kk=1: taps {4,5}/{6,7} — all valid.
  int tA[2], tB[2];
#pragma unroll
  for (int kk = 0; kk < 2; ++kk) {
    tA[kk] = tapoff(4 * kk + 2 * hi);
    tB[kk] = tapoff(4 * kk + 2 * hi + 1);
  }
  s16x8 wb[3];
#pragma unroll
  for (int kk = 0; kk < 3; ++kk)
    wb[kk] = *(const s16x8*)&wt1n[oc * 48 + kk * 16 + hi * 8];
  const float bias = cb[oc];
  float s = 0.f, ss = 0.f;
  for (int mt = wave; mt < 29; mt += 4) {
    const int boff = tbl1[mt * 32 + (lane & 31)];
    f32x16 acc;
#pragma unroll
    for (int r = 0; r < 16; ++r) acc[r] = bias;
#pragma unroll
    for (int kk = 0; kk < 2; ++kk) {
      AU a;
      *(uint2*)&a.e[0] = *(const uint2*)&xsb4[boff + tA[kk]];
      *(uint2*)&a.e[4] = *(const uint2*)&xsb4[boff + tB[kk]];
      acc = __builtin_amdgcn_mfma_f32_32x32x16_bf16(a.v, wb[kk], acc, 0, 0, 0);
    }
    {   // kk=2: only tap 8 (hi=0 low half) real; rest zero (B is zero there too)
      AU a;
#pragma unroll
      for (int j = 0; j < 8; ++j) a.e[j] = 0;
      if (hi == 0) *(uint2*)&a.e[0] = *(const uint2*)&xsb4[boff + 264];  // tapoff(8)
      acc = __builtin_amdgcn_mfma_f32_32x32x16_bf16(a.v, wb[2], acc, 0, 0, 0);
    }
#pragma unroll
    for (int reg = 0; reg < 16; ++reg) {
      const int row = mt * 32 + (reg & 3) + 8 * (reg >> 2) + 4 * hi;
      if (row < 900) { s += acc[reg]; ss += acc[reg] * acc[reg]; }
    }
  }
  s += __shfl_down(s, 32); ss += __shfl_down(ss, 32);
  if (lane < 32) { atomicAdd(&csum[oc], s); atomicAdd(&css[oc], ss); }
  __syncthreads();
  if (tid < 32) {
    part1[tid * 2048 + n] = csum[tid];
    part1[(32 + tid) * 2048 + n] = css[tid];
  }
}

// ---------------------------------------------------------------- K2: conv1 apply (32x32) -> p1 (LDS) + conv2 (32x32) -> y2s + part2
__global__ __launch_bounds__(256, 4) void conv1_apply_conv2_stats(
    const float* __restrict__ x, const us* __restrict__ wt1n,
    const float* __restrict__ cb1, const float* __restrict__ stats1,
    const us* __restrict__ wt2L, const float* __restrict__ cb2,
    float* __restrict__ part2, us* __restrict__ y2s) {
  __shared__ __align__(16) us xsb4[4096];
  __shared__ __align__(16) us p1b[9000];      // [225][40]
  __shared__ us tbl1[928];
  __shared__ us tbl2[192];
  __shared__ float scS[32], shS[32], csum[32], css[32];
  const int n = blockIdx.x, tid = threadIdx.x;
  const int wave = tid >> 6, lane = tid & 63, oc = lane & 31, hi = lane >> 5;
  stage_x_cminor(x + (size_t)n * 3072, xsb4, tid);
  build_tbl1(tbl1, tid);
  if (tid < 192) {                            // conv2 permuted-row input-pixel table
    us v = 0;
    const int q = tid;
    if (q < 144) {
      const int w = q >> 2, e = q & 3;
      v = (us)((2 * (w / 6) + (e >> 1)) * 15 + 2 * (w % 6) + (e & 1));
    } else if (q < 169) {
      const int r = q - 144;
      v = (us)((r < 13) ? (12 * 15 + r) : ((r - 13) * 15 + 12));
    }
    tbl2[tid] = v;
  }
  if (tid < 32) {
    scS[tid] = stats1[tid]; shS[tid] = stats1[32 + tid];
    csum[tid] = 0.f; css[tid] = 0.f;
  }
  __syncthreads();
  // ---- conv1 apply + bn1+relu+pool1 -> p1b
  {
    int tA[2], tB[2];
#pragma unroll
    for (int kk = 0; kk < 2; ++kk) {
      tA[kk] = tapoff(4 * kk + 2 * hi);
      tB[kk] = tapoff(4 * kk + 2 * hi + 1);
    }
    s16x8 wb[3];
#pragma unroll
    for (int kk = 0; kk < 3; ++kk)
      wb[kk] = *(const s16x8*)&wt1n[oc * 48 + kk * 16 + hi * 8];
    const float bias = cb1[oc];
    const float sc = scS[oc], sh = shS[oc];
    for (int mt = wave; mt < 29; mt += 4) {
      const int boff = tbl1[mt * 32 + (lane & 31)];
      f32x16 acc;
#pragma unroll
      for (int r = 0; r < 16; ++r) acc[r] = bias;
#pragma unroll
      for (int kk = 0; kk < 2; ++kk) {
        AU a;
        *(uint2*)&a.e[0] = *(const uint2*)&xsb4[boff + tA[kk]];
        *(uint2*)&a.e[4] = *(const uint2*)&xsb4[boff + tB[kk]];
        acc = __builtin_amdgcn_mfma_f32_32x32x16_bf16(a.v, wb[kk], acc, 0, 0, 0);
      }
      {   // kk=2: only tap 8 real
        AU a;
#pragma unroll
        for (int j = 0; j < 8; ++j) a.e[j] = 0;
        if (hi == 0) *(uint2*)&a.e[0] = *(const uint2*)&xsb4[boff + 264];
        acc = __builtin_amdgcn_mfma_f32_32x32x16_bf16(a.v, wb[2], acc, 0, 0, 0);
      }
#pragma unroll
      for (int q = 0; q < 4; ++q) {
        const int w = mt * 8 + 2 * q + hi;    // pool window 0..224
        if (w < 225) {
          float p = 0.f;
#pragma unroll
          for (int r = 0; r < 4; ++r) p += fmaxf(acc[q * 4 + r] * sc + sh, 0.f);
          p1b[w * 40 + oc] = f2bf1(p * 0.25f);
        }
      }
    }
  }
  __syncthreads();
  // ---- conv2 (6 tiles of 32 permuted rows) -> y2s + stats
  {
    const float bias2 = cb2[oc];
    float s = 0.f, ss = 0.f;
    for (int mt2 = wave; mt2 < 6; mt2 += 4) {
      const int inb = tbl2[mt2 * 32 + (lane & 31)];
      f32x16 acc;
#pragma unroll
      for (int r = 0; r < 16; ++r) acc[r] = bias2;
#pragma unroll
      for (int tap = 0; tap < 9; ++tap) {
        const int ki = tap / 3, kj = tap % 3;
#pragma unroll
        for (int kk = 0; kk < 2; ++kk) {
          const s16x8 a = *(const s16x8*)&p1b[(inb + ki * 15 + kj) * 40 + kk * 16 + hi * 8];
          const s16x8 b = *(const s16x8*)&wt2L[(tap * 32 + oc) * 40 + kk * 16 + hi * 8];
          acc = __builtin_amdgcn_mfma_f32_32x32x16_bf16(a, b, acc, 0, 0, 0);
        }
      }
#pragma unroll
      for (int q = 0; q < 4; ++q) {
        const int wloc = mt2 * 8 + 2 * q + hi;
        if (wloc < 36) {                      // window px -> y2s [n][w][c][4e]
          uint2 pk;
          pk.x = cvtpk(acc[q * 4 + 0], acc[q * 4 + 1]);
          pk.y = cvtpk(acc[q * 4 + 2], acc[q * 4 + 3]);
          *(uint2*)(y2s + (((size_t)n * 36 + wloc) * 32 + oc) * 4) = pk;
        }
      }
#pragma unroll
      for (int reg = 0; reg < 16; ++reg) {
        const int row = mt2 * 32 + (reg & 3) + 8 * (reg >> 2) + 4 * hi;
        if (row < 169) { s += acc[reg]; ss += acc[reg] * acc[reg]; }
      }
    }
    s += __shfl_down(s, 32); ss += __shfl_down(ss, 32);
    if (lane < 32) { atomicAdd(&csum[oc], s); atomicAdd(&css[oc], ss); }
  }
  __syncthreads();
  if (tid < 32) {
    part2[tid * 2048 + n] = csum[tid];
    part2[(32 + tid) * 2048 + n] = css[tid];
  }
}

// ---------------------------------------------------------------- K3: bnpool2 (from y2s) -> p2 + conv3 partials (8 samples/block)
__global__ __launch_bounds__(256) void bnpool2_conv3_stats(
    const us* __restrict__ y2s, const float* __restrict__ stats2,
    const us* __restrict__ wt3L, const float* __restrict__ cb3,
    float* __restrict__ part3, us* __restrict__ p2g) {
  __shared__ __align__(16) us p2L[11520];      // [8][36][40]
  __shared__ float scS[32], shS[32], csum[32], css[32];
  const int n0 = blockIdx.x * 8, tid = threadIdx.x;
  const int wave = tid >> 6, lane = tid & 63, row16 = lane & 15, kg = lane >> 4;
  if (tid < 32) {
    scS[tid] = stats2[tid]; shS[tid] = stats2[32 + tid];
    csum[tid] = 0.f; css[tid] = 0.f;
  }
  __syncthreads();
#pragma unroll
  for (int it = 0; it < 36; ++it) {
    const int i = tid + it * 256;
    const int c = i & 31, w = (i >> 5) % 36, s = i / 1152;
    const uint2 v = *(const uint2*)(y2s + (((size_t)(n0 + s) * 36 + w) * 32 + c) * 4);
    const float sc = scS[c], sh = shS[c];
    const float p = fmaxf(bflo(v.x) * sc + sh, 0.f) + fmaxf(bfhi(v.x) * sc + sh, 0.f) +
                    fmaxf(bflo(v.y) * sc + sh, 0.f) + fmaxf(bfhi(v.y) * sc + sh, 0.f);
    const us pb = f2bf1(p * 0.25f);
    p2L[(s * 36 + w) * 40 + c] = pb;
    p2g[((size_t)(n0 + s) * 36 + w) * 32 + c] = pb;
  }
  __syncthreads();
  const int inb3 = (row16 >> 2) * 6 + (row16 & 3);
  const float b30 = cb3[row16], b31 = cb3[16 + row16];
  float s0 = 0.f, ss0 = 0.f, s1 = 0.f, ss1 = 0.f;
#pragma unroll
  for (int si = 0; si < 2; ++si) {
    const int s = wave * 2 + si;
    f32x4 a0 = {b30, b30, b30, b30};
    f32x4 a1 = {b31, b31, b31, b31};
#pragma unroll
    for (int tap = 0; tap < 9; ++tap) {
      const int ki = tap / 3, kj = tap % 3;
      const s16x8 wf0 = *(const s16x8*)&wt3L[(tap * 32 + row16) * 40 + kg * 8];
      const s16x8 wf1 = *(const s16x8*)&wt3L[(tap * 32 + 16 + row16) * 40 + kg * 8];
      const s16x8 a = *(const s16x8*)&p2L[(s * 36 + inb3 + ki * 6 + kj) * 40 + kg * 8];
      a0 = __builtin_amdgcn_mfma_f32_16x16x32_bf16(a, wf0, a0, 0, 0, 0);
      a1 = __builtin_amdgcn_mfma_f32_16x16x32_bf16(a, wf1, a1, 0, 0, 0);
    }
#pragma unroll
    for (int r = 0; r < 4; ++r) {
      s0 += a0[r]; ss0 += a0[r] * a0[r];
      s1 += a1[r]; ss1 += a1[r] * a1[r];
    }
  }
  s0 += __shfl_down(s0, 32); s0 += __shfl_down(s0, 16);
  ss0 += __shfl_down(ss0, 32); ss0 += __shfl_down(ss0, 16);
  s1 += __shfl_down(s1, 32); s1 += __shfl_down(s1, 16);
  ss1 += __shfl_down(ss1, 32); ss1 += __shfl_down(ss1, 16);
  if (lane < 16) {
    atomicAdd(&csum[row16], s0); atomicAdd(&css[row16], ss0);
    atomicAdd(&csum[16 + row16], s1); atomicAdd(&css[16 + row16], ss1);
  }
  __syncthreads();
  if (tid < 32) {
    part3[tid * 2048 + blockIdx.x] = csum[tid];
    part3[(32 + tid) * 2048 + blockIdx.x] = css[tid];
  }
}

// ---------------------------------------------------------------- finalize for K3's 256-block partials
__global__ __launch_bounds__(256) void finalize_stats256(
    const float* __restrict__ part, const float* __restrict__ g,
    const float* __restrict__ bb, float cnt, float* __restrict__ stats) {
  __shared__ float redS[256], redQ[256];
  const int ch = blockIdx.x, tid = threadIdx.x;
  const float* ps = part + (size_t)ch * 2048;
  const float* pq = part + (size_t)(32 + ch) * 2048;
  redS[tid] = ps[tid]; redQ[tid] = pq[tid];
  __syncthreads();
  for (int off = 128; off; off >>= 1) {
    if (tid < off) { redS[tid] += redS[tid + off]; redQ[tid] += redQ[tid + off]; }
    __syncthreads();
  }
  if (tid == 0) {
    const float mean = redS[0] / cnt;
    const float var = redQ[0] / cnt - mean * mean;
    const float sc = g[ch] * rsqrtf(var + EPSV);
    stats[ch] = sc;
    stats[32 + ch] = bb[ch] - mean * sc;
  }
}

// ---------------------------------------------------------------- K4: conv3 apply + routed MLP fused (8 samples/block, 1 wave)
__global__ __launch_bounds__(64) void conv3_apply_mlp(
    const us* __restrict__ p2g, const us* __restrict__ wt3L,
    const float* __restrict__ cb3, const float* __restrict__ stats3,
    const float* __restrict__ traj,
    const us* __restrict__ ewB, const float* __restrict__ eb,
    const us* __restrict__ owB, const float* __restrict__ ob,
    float* __restrict__ out) {
  __shared__ __align__(16) us p2L[11520];      // [8][36][40]
  __shared__ float h0a[1024];                  // [8][128]
  __shared__ __align__(16) us ht[16 * 136];
  __shared__ float scS[32], shS[32], ebl[384], obl[112];
  const int lane = threadIdx.x, row16 = lane & 15, kg = lane >> 4;
  const int n0 = blockIdx.x * 8, rbase = blockIdx.x * 16;
  for (int i = lane; i < 1152; i += 64) {
    const int s = i / 144, ci = i - s * 144;
    const uint4 v = ((const uint4*)(p2g + (size_t)n0 * 1152))[i];
    *(uint4*)&p2L[(s * 36 + (ci >> 2)) * 40 + (ci & 3) * 8] = v;
  }
  if (lane < 32) { scS[lane] = stats3[lane]; shS[lane] = stats3[32 + lane]; }
  for (int i = lane; i < 384; i += 64) ebl[i] = eb[i];
  for (int i = lane; i < 112; i += 64) obl[i] = (i < 100) ? ob[i] : 0.f;
  __syncthreads();
  const int wA = row16 >> 2, eA = row16 & 3;
  const int inb3 = (2 * (wA >> 1) + (eA >> 1)) * 6 + 2 * (wA & 1) + (eA & 1);
  const float b30 = cb3[row16], b31 = cb3[16 + row16];
  const float sc0 = scS[row16], sh0 = shS[row16];
  const float sc1 = scS[16 + row16], sh1 = shS[16 + row16];
#pragma unroll
  for (int s = 0; s < 8; ++s) {
    f32x4 a0 = {b30, b30, b30, b30};
    f32x4 a1 = {b31, b31, b31, b31};
#pragma unroll
    for (int tap = 0; tap < 9; ++tap) {
      const int ki = tap / 3, kj = tap % 3;
      const s16x8 wf0 = *(const s16x8*)&wt3L[(tap * 32 + row16) * 40 + kg * 8];
      const s16x8 wf1 = *(const s16x8*)&wt3L[(tap * 32 + 16 + row16) * 40 + kg * 8];
      const s16x8 a = *(const s16x8*)&p2L[(s * 36 + inb3 + ki * 6 + kj) * 40 + kg * 8];
      a0 = __builtin_amdgcn_mfma_f32_16x16x32_bf16(a, wf0, a0, 0, 0, 0);
      a1 = __builtin_amdgcn_mfma_f32_16x16x32_bf16(a, wf1, a1, 0, 0, 0);
    }
    float p0 = 0.f, p1v = 0.f;
#pragma unroll
    for (int r = 0; r < 4; ++r) {
      p0 += fmaxf(a0[r] * sc0 + sh0, 0.f);
      p1v += fmaxf(a1[r] * sc1 + sh1, 0.f);
    }
    h0a[s * 128 + row16 * 4 + kg] = p0 * 0.25f;
    h0a[s * 128 + (16 + row16) * 4 + kg] = p1v * 0.25f;
  }
  __syncthreads();
#pragma unroll
  for (int q = 0; q < 4; ++q) {
    const int u = lane + q * 64;
    const int lr = u >> 4, d8 = (u & 15) * 8;
    const float* hp = &h0a[(lr >> 1) * 128 + d8];
    uint4 p;
    p.x = cvtpk(hp[0], hp[1]); p.y = cvtpk(hp[2], hp[3]);
    p.z = cvtpk(hp[4], hp[5]); p.w = cvtpk(hp[6], hp[7]);
    *(uint4*)&ht[lr * 136 + d8] = p;
  }
  float accv[8][4];
#pragma unroll
  for (int ct = 0; ct < 8; ++ct)
#pragma unroll
    for (int r = 0; r < 4; ++r)
      accv[ct][r] = h0a[((kg * 4 + r) >> 1) * 128 + ct * 16 + row16];
  __syncthreads();
  for (int d = 0; d < 3; ++d) {
    int sel[4];
#pragma unroll
    for (int r = 0; r < 4; ++r) {
      const int rowg = rbase + kg * 4 + r;
      const float4 t4 = *(const float4*)(traj + d * 16384 + rowg * 4);
      int s = 0; float mx = t4.x;
      if (t4.y > mx) { mx = t4.y; s = 1; }
      if (t4.z > mx) { mx = t4.z; s = 2; }
      if (t4.w > mx) { mx = t4.w; s = 3; }
      sel[r] = s;
    }
    s16x8 a[4];
#pragma unroll
    for (int kc = 0; kc < 4; ++kc)
      a[kc] = *(const s16x8*)&ht[row16 * 136 + kc * 32 + kg * 8];
    float newacc[8][4];
#pragma unroll
    for (int ct = 0; ct < 8; ++ct)
#pragma unroll
      for (int r = 0; r < 4; ++r)
        newacc[ct][r] = (sel[r] == 3) ? accv[ct][r] : 0.f;
#pragma unroll
    for (int e = 0; e < 3; ++e) {
#pragma unroll
      for (int ct = 0; ct < 8; ++ct) {
        f32x4 t = {0.f, 0.f, 0.f, 0.f};
#pragma unroll
        for (int kc = 0; kc < 4; ++kc) {
          const s16x8 b = *(const s16x8*)&ewB[(e * 128 + ct * 16 + row16) * 128 + kc * 32 + kg * 8];
          t = __builtin_amdgcn_mfma_f32_16x16x32_bf16(a[kc], b, t, 0, 0, 0);
        }
        const float bias = ebl[e * 128 + ct * 16 + row16];
#pragma unroll
        for (int r = 0; r < 4; ++r)
          if (sel[r] == e) newacc[ct][r] = t[r] + bias;
      }
    }
#pragma unroll
    for (int ct = 0; ct < 8; ++ct)
#pragma unroll
      for (int r = 0; r < 4; ++r) {
        float v = newacc[ct][r];
        if (d < 2) v = fmaxf(v, 0.f);
        accv[ct][r] = v;
        ht[(kg * 4 + r) * 136 + ct * 16 + row16] = f2bf1(v);
      }
  }
  s16x8 a[4];
#pragma unroll
  for (int kc = 0; kc < 4; ++kc)
    a[kc] = *(const s16x8*)&ht[row16 * 136 + kc * 32 + kg * 8];
  float preds[7][4];
#pragma unroll
  for (int ct = 0; ct < 7; ++ct) {
    f32x4 t = {0.f, 0.f, 0.f, 0.f};
#pragma unroll
    for (int kc = 0; kc < 4; ++kc) {
      const s16x8 b = *(const s16x8*)&owB[(ct * 16 + row16) * 128 + kc * 32 + kg * 8];
      t = __builtin_amdgcn_mfma_f32_16x16x32_bf16(a[kc], b, t, 0, 0, 0);
    }
    const float bias = obl[ct * 16 + row16];
#pragma unroll
    for (int r = 0; r < 4; ++r) preds[ct][r] = t[r] + bias;
  }
  const bool v6 = (96 + row16) < 100;
#pragma unroll
  for (int r = 0; r < 4; ++r) {
    float mx = -INFINITY;
#pragma unroll
    for (int ct = 0; ct < 7; ++ct)
      if (ct < 6 || v6) mx = fmaxf(mx, preds[ct][r]);
    mx = fmaxf(mx, __shfl_xor(mx, 1)); mx = fmaxf(mx, __shfl_xor(mx, 2));
    mx = fmaxf(mx, __shfl_xor(mx, 4)); mx = fmaxf(mx, __shfl_xor(mx, 8));
    float s = 0.f;
#pragma unroll
    for (int ct = 0; ct < 7; ++ct)
      if (ct < 6 || v6) s += expf(preds[ct][r] - mx);
    s += __shfl_xor(s, 1); s += __shfl_xor(s, 2);
    s += __shfl_xor(s, 4); s += __shfl_xor(s, 8);
    const float lg = mx + logf(s);
    const int rowg = rbase + kg * 4 + r;
#pragma unroll
    for (int ct = 0; ct < 7; ++ct)
      if (ct < 6 || v6) out[(size_t)rowg * 100 + ct * 16 + row16] = preds[ct][r] - lg;
  }
}

// ---------------------------------------------------------------- launch
extern "C" void kernel_launch(void* const* d_in, const int* in_sizes, int n_in,
                              void* d_out, int out_size, void* d_ws, size_t ws_size,
                              hipStream_t stream) {
  const float* x     = (const float*)d_in[0];
  const float* traj  = (const float*)d_in[1];
  const float* score = (const float*)d_in[2];
  const float* cw1 = (const float*)d_in[3];
  const float* cb1 = (const float*)d_in[4];
  const float* g1  = (const float*)d_in[5];
  const float* bb1 = (const float*)d_in[6];
  const float* cw2 = (const float*)d_in[7];
  const float* cb2 = (const float*)d_in[8];
  const float* g2  = (const float*)d_in[9];
  const float* bb2 = (const float*)d_in[10];
  const float* cw3 = (const float*)d_in[11];
  const float* cb3 = (const float*)d_in[12];
  const float* g3  = (const float*)d_in[13];
  const float* bb3 = (const float*)d_in[14];
  const float* eW  = (const float*)d_in[15];
  const float* eb  = (const float*)d_in[16];
  const float* oW  = (const float*)d_in[17];
  const float* ob  = (const float*)d_in[18];
  float* out = (float*)d_out;

  char* ws = (char*)d_ws;
  float* stats1 = (float*)ws;
  float* stats2 = (float*)(ws + 256);
  float* stats3 = (float*)(ws + 512);
  us* wt1n  = (us*)(ws + 1024);
  us* wt2L  = (us*)(ws + 8192);
  us* wt3L  = (us*)(ws + 8192 + 23040);
  us* ewB   = (us*)(ws + 65536);
  us* owB   = (us*)(ws + 65536 + 98304);
  us* y2s   = (us*)(ws + 262144);                // bf16 [2048][36][32][4]
  us* p2g   = (us*)(ws + 262144 + 18874368);     // bf16 [2048][36][32]
  char* pbase = ws + 262144 + 18874368 + 4718592;
  float* part1 = (float*)pbase;
  float* part2 = (float*)(pbase + 524288);
  float* part3 = (float*)(pbase + 1048576);

  prep_weights<<<64, 256, 0, stream>>>(cw1, cw2, cw3, eW, oW,
                                       wt1n, wt2L, wt3L, ewB, owB);
  conv1_stats<<<2048, 256, 0, stream>>>(x, wt1n, cb1, part1);
  finalize_stats<<<32, 256, 0, stream>>>(part1, g1, bb1, 2048.f * 900.f, stats1);
  conv1_apply_conv2_stats<<<2048, 256, 0, stream>>>(x, wt1n, cb1, stats1,
                                                    wt2L, cb2, part2, y2s);
  finalize_stats<<<32, 256, 0, stream>>>(part2, g2, bb2, 2048.f * 169.f, stats2);
  bnpool2_conv3_stats<<<256, 256, 0, stream>>>(y2s, stats2, wt3L, cb3, part3, p2g);
  finalize_stats256<<<32, 256, 0, stream>>>(part3, g3, bb3, 2048.f * 16.f, stats3);
  conv3_apply_mlp<<<256, 64, 0, stream>>>(p2g, wt3L, cb3, stats3, traj,
                                          ewB, eb, owB, ob, out);
  hipMemcpyAsync(out + 409600, score, 4096 * sizeof(float),
                 hipMemcpyDeviceToDevice, stream);
}

// Round 20
// 96.158 us; speedup vs baseline: 1.2013x; 1.0176x over previous
//
#include <hip/hip_runtime.h>
#include <math.h>

typedef unsigned short us;
typedef short s16x8 __attribute__((ext_vector_type(8)));
typedef float f32x4 __attribute__((ext_vector_type(4)));
typedef float f32x16 __attribute__((ext_vector_type(16)));

#define EPSV 1e-5f

static __device__ inline us f2bf(float f) {            // RNE f32->bf16 (prep only)
  union { float f; unsigned u; } v; v.f = f;
  unsigned r = v.u + 0x7fffu + ((v.u >> 16) & 1u);
  return (us)(r >> 16);
}
static __device__ inline unsigned cvtpk(float lo, float hi) {
  unsigned r;
  asm("v_cvt_pk_bf16_f32 %0, %1, %2" : "=v"(r) : "v"(lo), "v"(hi));
  return r;
}
static __device__ inline us f2bf1(float f) { return (us)cvtpk(f, 0.f); }
static __device__ inline float bflo(unsigned u) { return __uint_as_float(u << 16); }
static __device__ inline float bfhi(unsigned u) { return __uint_as_float(u & 0xffff0000u); }

union AU { s16x8 v; us e[8]; };

// ---------------------------------------------------------------- K0: preconvert weights + score passthrough
// wt1n[32oc][48k]: k = tap*4 + c (tap<9, c<3 real; else 0)
// wt2L/wt3L[(tap*32+oc)][40]; ewB[3*128*128]; owB[112*128]
__global__ __launch_bounds__(256) void prep_weights(
    const float* __restrict__ w1, const float* __restrict__ w2,
    const float* __restrict__ w3, const float* __restrict__ eW,
    const float* __restrict__ oW, const float* __restrict__ score,
    us* __restrict__ wt1n, us* __restrict__ wt2L, us* __restrict__ wt3L,
    us* __restrict__ ewB, us* __restrict__ owB, float* __restrict__ outScore) {
  const int gtid = blockIdx.x * 256 + threadIdx.x;
  const int G = gridDim.x * 256;
  for (int i = gtid; i < 1536; i += G) {
    const int oc = i / 48, k = i % 48, t = k >> 2, c = k & 3;
    wt1n[i] = (t < 9 && c < 3) ? f2bf(w1[oc * 27 + c * 9 + t]) : (us)0;
  }
  for (int i = gtid; i < 11520; i += G) {
    const int row = i / 40, col = i % 40;
    const int tap = row >> 5, oc = row & 31;
    wt2L[i] = (col < 32) ? f2bf(w2[oc * 288 + col * 9 + tap]) : (us)0;
    wt3L[i] = (col < 32) ? f2bf(w3[oc * 288 + col * 9 + tap]) : (us)0;
  }
  for (int i = gtid; i < 49152; i += G) ewB[i] = f2bf(eW[i]);
  for (int i = gtid; i < 14336; i += G) {
    const int cls = i >> 7;
    owB[i] = (cls < 100) ? f2bf(oW[cls * 128 + (i & 127)]) : (us)0;
  }
  for (int i = gtid; i < 4096; i += G) outScore[i] = score[i];
}

// ---------------------------------------------------------------- finalize: partials[ch][2048] -> {scale, shift}
__global__ __launch_bounds__(256) void finalize_stats(
    const float* __restrict__ part, const float* __restrict__ g,
    const float* __restrict__ bb, float cnt, float* __restrict__ stats) {
  __shared__ float redS[256], redQ[256];
  const int ch = blockIdx.x, tid = threadIdx.x;
  const float* ps = part + (size_t)ch * 2048;
  const float* pq = part + (size_t)(32 + ch) * 2048;
  float s = 0.f, q = 0.f;
  for (int i = tid; i < 2048; i += 256) { s += ps[i]; q += pq[i]; }
  redS[tid] = s; redQ[tid] = q;
  __syncthreads();
  for (int off = 128; off; off >>= 1) {
    if (tid < off) { redS[tid] += redS[tid + off]; redQ[tid] += redQ[tid + off]; }
    __syncthreads();
  }
  if (tid == 0) {
    const float mean = redS[0] / cnt;
    const float var = redQ[0] / cnt - mean * mean;
    const float sc = g[ch] * rsqrtf(var + EPSV);
    stats[ch] = sc;
    stats[32 + ch] = bb[ch] - mean * sc;
  }
}

// conv1 helper: stage x c-minor [32][32][4] bf16
static __device__ inline void stage_x_cminor(const float* xp, us* xsb4, int tid) {
#pragma unroll
  for (int k = 0; k < 4; ++k) {
    const int p = tid + k * 256;
    const unsigned lo = cvtpk(xp[p], xp[1024 + p]);
    const unsigned hi = cvtpk(xp[2048 + p], 0.f);
    *(uint2*)&xsb4[p * 4] = make_uint2(lo, hi);
  }
}

// build conv1 permuted-row offset table (u16 element-offsets), entries 0..927
static __device__ inline void build_tbl1(us* tbl, int tid) {
  for (int i = tid; i < 928; i += 256) {
    us v = 0;
    if (i < 900) {
      const int w = i >> 2, e = i & 3;
      v = (us)((((2 * (w / 15) + (e >> 1)) * 32 + 2 * (w % 15) + (e & 1))) * 4);
    }
    tbl[i] = v;
  }
}

// tap (0..8 only) -> xsb4 element offset
static __device__ inline int tapoff(int t) {
  return ((t / 3) * 32 + t % 3) * 4;
}

// ---------------------------------------------------------------- K1: conv1 stats (32x32x16 MFMA, tap-packed K=48)
__global__ __launch_bounds__(256, 4) void conv1_stats(
    const float* __restrict__ x, const us* __restrict__ wt1n,
    const float* __restrict__ cb, float* __restrict__ part1) {
  __shared__ __align__(16) us xsb4[4096];
  __shared__ us tbl1[928];
  __shared__ float csum[32], css[32];
  const int n = blockIdx.x, tid = threadIdx.x;
  const int wave = tid >> 6, lane = tid & 63, oc = lane & 31, hi = lane >> 5;
  stage_x_cminor(x + (size_t)n * 3072, xsb4, tid);
  build_tbl1(tbl1, tid);
  if (tid < 32) { csum[tid] = 0.f; css[tid] = 0.f; }
  __syncthreads();
  int tA[2], tB[2];
#pragma unroll
  for (int kk = 0; kk < 2; ++kk) {
    tA[kk] = tapoff(4 * kk + 2 * hi);
    tB[kk] = tapoff(4 * kk + 2 * hi + 1);
  }
  s16x8 wb[3];
#pragma unroll
  for (int kk = 0; kk < 3; ++kk)
    wb[kk] = *(const s16x8*)&wt1n[oc * 48 + kk * 16 + hi * 8];
  const float bias = cb[oc];
  float s = 0.f, ss = 0.f;
  for (int mt = wave; mt < 29; mt += 4) {
    const int boff = tbl1[mt * 32 + (lane & 31)];
    f32x16 acc;
#pragma unroll
    for (int r = 0; r < 16; ++r) acc[r] = bias;
#pragma unroll
    for (int kk = 0; kk < 2; ++kk) {
      AU a;
      *(uint2*)&a.e[0] = *(const uint2*)&xsb4[boff + tA[kk]];
      *(uint2*)&a.e[4] = *(const uint2*)&xsb4[boff + tB[kk]];
      acc = __builtin_amdgcn_mfma_f32_32x32x16_bf16(a.v, wb[kk], acc, 0, 0, 0);
    }
    {   // kk=2: only tap 8 (hi=0 low half) real; rest zero (B is zero there too)
      AU a;
#pragma unroll
      for (int j = 0; j < 8; ++j) a.e[j] = 0;
      if (hi == 0) *(uint2*)&a.e[0] = *(const uint2*)&xsb4[boff + 264];  // tapoff(8)
      acc = __builtin_amdgcn_mfma_f32_32x32x16_bf16(a.v, wb[2], acc, 0, 0, 0);
    }
#pragma unroll
    for (int reg = 0; reg < 16; ++reg) {
      const int row = mt * 32 + (reg & 3) + 8 * (reg >> 2) + 4 * hi;
      if (row < 900) { s += acc[reg]; ss += acc[reg] * acc[reg]; }
    }
  }
  s += __shfl_down(s, 32); ss += __shfl_down(ss, 32);
  if (lane < 32) { atomicAdd(&csum[oc], s); atomicAdd(&css[oc], ss); }
  __syncthreads();
  if (tid < 32) {
    part1[tid * 2048 + n] = csum[tid];
    part1[(32 + tid) * 2048 + n] = css[tid];
  }
}

// ---------------------------------------------------------------- K2: conv1 apply (32x32) -> p1 (LDS) + conv2 (32x32) -> y2s + part2
__global__ __launch_bounds__(256, 4) void conv1_apply_conv2_stats(
    const float* __restrict__ x, const us* __restrict__ wt1n,
    const float* __restrict__ cb1, const float* __restrict__ stats1,
    const us* __restrict__ wt2L, const float* __restrict__ cb2,
    float* __restrict__ part2, us* __restrict__ y2s) {
  __shared__ __align__(16) us xsb4[4096];
  __shared__ __align__(16) us p1b[9000];      // [225][40]
  __shared__ us tbl1[928];
  __shared__ us tbl2[192];
  __shared__ float scS[32], shS[32], csum[32], css[32];
  const int n = blockIdx.x, tid = threadIdx.x;
  const int wave = tid >> 6, lane = tid & 63, oc = lane & 31, hi = lane >> 5;
  stage_x_cminor(x + (size_t)n * 3072, xsb4, tid);
  build_tbl1(tbl1, tid);
  if (tid < 192) {                            // conv2 permuted-row input-pixel table
    us v = 0;
    const int q = tid;
    if (q < 144) {
      const int w = q >> 2, e = q & 3;
      v = (us)((2 * (w / 6) + (e >> 1)) * 15 + 2 * (w % 6) + (e & 1));
    } else if (q < 169) {
      const int r = q - 144;
      v = (us)((r < 13) ? (12 * 15 + r) : ((r - 13) * 15 + 12));
    }
    tbl2[tid] = v;
  }
  if (tid < 32) {
    scS[tid] = stats1[tid]; shS[tid] = stats1[32 + tid];
    csum[tid] = 0.f; css[tid] = 0.f;
  }
  __syncthreads();
  // ---- conv1 apply + bn1+relu+pool1 -> p1b
  {
    int tA[2], tB[2];
#pragma unroll
    for (int kk = 0; kk < 2; ++kk) {
      tA[kk] = tapoff(4 * kk + 2 * hi);
      tB[kk] = tapoff(4 * kk + 2 * hi + 1);
    }
    s16x8 wb[3];
#pragma unroll
    for (int kk = 0; kk < 3; ++kk)
      wb[kk] = *(const s16x8*)&wt1n[oc * 48 + kk * 16 + hi * 8];
    const float bias = cb1[oc];
    const float sc = scS[oc], sh = shS[oc];
    for (int mt = wave; mt < 29; mt += 4) {
      const int boff = tbl1[mt * 32 + (lane & 31)];
      f32x16 acc;
#pragma unroll
      for (int r = 0; r < 16; ++r) acc[r] = bias;
#pragma unroll
      for (int kk = 0; kk < 2; ++kk) {
        AU a;
        *(uint2*)&a.e[0] = *(const uint2*)&xsb4[boff + tA[kk]];
        *(uint2*)&a.e[4] = *(const uint2*)&xsb4[boff + tB[kk]];
        acc = __builtin_amdgcn_mfma_f32_32x32x16_bf16(a.v, wb[kk], acc, 0, 0, 0);
      }
      {   // kk=2: only tap 8 real
        AU a;
#pragma unroll
        for (int j = 0; j < 8; ++j) a.e[j] = 0;
        if (hi == 0) *(uint2*)&a.e[0] = *(const uint2*)&xsb4[boff + 264];
        acc = __builtin_amdgcn_mfma_f32_32x32x16_bf16(a.v, wb[2], acc, 0, 0, 0);
      }
#pragma unroll
      for (int q = 0; q < 4; ++q) {
        const int w = mt * 8 + 2 * q + hi;    // pool window 0..224
        if (w < 225) {
          float p = 0.f;
#pragma unroll
          for (int r = 0; r < 4; ++r) p += fmaxf(acc[q * 4 + r] * sc + sh, 0.f);
          p1b[w * 40 + oc] = f2bf1(p * 0.25f);
        }
      }
    }
  }
  __syncthreads();
  // ---- conv2 (6 tiles of 32 permuted rows) -> y2s + stats
  {
    const float bias2 = cb2[oc];
    float s = 0.f, ss = 0.f;
    for (int mt2 = wave; mt2 < 6; mt2 += 4) {
      const int inb = tbl2[mt2 * 32 + (lane & 31)];
      f32x16 acc;
#pragma unroll
      for (int r = 0; r < 16; ++r) acc[r] = bias2;
#pragma unroll
      for (int tap = 0; tap < 9; ++tap) {
        const int ki = tap / 3, kj = tap % 3;
#pragma unroll
        for (int kk = 0; kk < 2; ++kk) {
          const s16x8 a = *(const s16x8*)&p1b[(inb + ki * 15 + kj) * 40 + kk * 16 + hi * 8];
          const s16x8 b = *(const s16x8*)&wt2L[(tap * 32 + oc) * 40 + kk * 16 + hi * 8];
          acc = __builtin_amdgcn_mfma_f32_32x32x16_bf16(a, b, acc, 0, 0, 0);
        }
      }
#pragma unroll
      for (int q = 0; q < 4; ++q) {
        const int wloc = mt2 * 8 + 2 * q + hi;
        if (wloc < 36) {                      // window px -> y2s [n][w][c][4e]
          uint2 pk;
          pk.x = cvtpk(acc[q * 4 + 0], acc[q * 4 + 1]);
          pk.y = cvtpk(acc[q * 4 + 2], acc[q * 4 + 3]);
          *(uint2*)(y2s + (((size_t)n * 36 + wloc) * 32 + oc) * 4) = pk;
        }
      }
#pragma unroll
      for (int reg = 0; reg < 16; ++reg) {
        const int row = mt2 * 32 + (reg & 3) + 8 * (reg >> 2) + 4 * hi;
        if (row < 169) { s += acc[reg]; ss += acc[reg] * acc[reg]; }
      }
    }
    s += __shfl_down(s, 32); ss += __shfl_down(ss, 32);
    if (lane < 32) { atomicAdd(&csum[oc], s); atomicAdd(&css[oc], ss); }
  }
  __syncthreads();
  if (tid < 32) {
    part2[tid * 2048 + n] = csum[tid];
    part2[(32 + tid) * 2048 + n] = css[tid];
  }
}

// ---------------------------------------------------------------- K3: bnpool2 (from y2s) -> p2 + conv3 partials (8 samples/block)
__global__ __launch_bounds__(256) void bnpool2_conv3_stats(
    const us* __restrict__ y2s, const float* __restrict__ stats2,
    const us* __restrict__ wt3L, const float* __restrict__ cb3,
    float* __restrict__ part3, us* __restrict__ p2g) {
  __shared__ __align__(16) us p2L[11520];      // [8][36][40]
  __shared__ float scS[32], shS[32], csum[32], css[32];
  const int n0 = blockIdx.x * 8, tid = threadIdx.x;
  const int wave = tid >> 6, lane = tid & 63, row16 = lane & 15, kg = lane >> 4;
  if (tid < 32) {
    scS[tid] = stats2[tid]; shS[tid] = stats2[32 + tid];
    csum[tid] = 0.f; css[tid] = 0.f;
  }
  __syncthreads();
#pragma unroll
  for (int it = 0; it < 36; ++it) {
    const int i = tid + it * 256;
    const int c = i & 31, w = (i >> 5) % 36, s = i / 1152;
    const uint2 v = *(const uint2*)(y2s + (((size_t)(n0 + s) * 36 + w) * 32 + c) * 4);
    const float sc = scS[c], sh = shS[c];
    const float p = fmaxf(bflo(v.x) * sc + sh, 0.f) + fmaxf(bfhi(v.x) * sc + sh, 0.f) +
                    fmaxf(bflo(v.y) * sc + sh, 0.f) + fmaxf(bfhi(v.y) * sc + sh, 0.f);
    const us pb = f2bf1(p * 0.25f);
    p2L[(s * 36 + w) * 40 + c] = pb;
    p2g[((size_t)(n0 + s) * 36 + w) * 32 + c] = pb;
  }
  __syncthreads();
  const int inb3 = (row16 >> 2) * 6 + (row16 & 3);
  const float b30 = cb3[row16], b31 = cb3[16 + row16];
  float s0 = 0.f, ss0 = 0.f, s1 = 0.f, ss1 = 0.f;
#pragma unroll
  for (int si = 0; si < 2; ++si) {
    const int s = wave * 2 + si;
    f32x4 a0 = {b30, b30, b30, b30};
    f32x4 a1 = {b31, b31, b31, b31};
#pragma unroll
    for (int tap = 0; tap < 9; ++tap) {
      const int ki = tap / 3, kj = tap % 3;
      const s16x8 wf0 = *(const s16x8*)&wt3L[(tap * 32 + row16) * 40 + kg * 8];
      const s16x8 wf1 = *(const s16x8*)&wt3L[(tap * 32 + 16 + row16) * 40 + kg * 8];
      const s16x8 a = *(const s16x8*)&p2L[(s * 36 + inb3 + ki * 6 + kj) * 40 + kg * 8];
      a0 = __builtin_amdgcn_mfma_f32_16x16x32_bf16(a, wf0, a0, 0, 0, 0);
      a1 = __builtin_amdgcn_mfma_f32_16x16x32_bf16(a, wf1, a1, 0, 0, 0);
    }
#pragma unroll
    for (int r = 0; r < 4; ++r) {
      s0 += a0[r]; ss0 += a0[r] * a0[r];
      s1 += a1[r]; ss1 += a1[r] * a1[r];
    }
  }
  s0 += __shfl_down(s0, 32); s0 += __shfl_down(s0, 16);
  ss0 += __shfl_down(ss0, 32); ss0 += __shfl_down(ss0, 16);
  s1 += __shfl_down(s1, 32); s1 += __shfl_down(s1, 16);
  ss1 += __shfl_down(ss1, 32); ss1 += __shfl_down(ss1, 16);
  if (lane < 16) {
    atomicAdd(&csum[row16], s0); atomicAdd(&css[row16], ss0);
    atomicAdd(&csum[16 + row16], s1); atomicAdd(&css[16 + row16], ss1);
  }
  __syncthreads();
  if (tid < 32) {
    part3[tid * 2048 + blockIdx.x] = csum[tid];
    part3[(32 + tid) * 2048 + blockIdx.x] = css[tid];
  }
}

// ---------------------------------------------------------------- finalize for K3's 256-block partials
__global__ __launch_bounds__(256) void finalize_stats256(
    const float* __restrict__ part, const float* __restrict__ g,
    const float* __restrict__ bb, float cnt, float* __restrict__ stats) {
  __shared__ float redS[256], redQ[256];
  const int ch = blockIdx.x, tid = threadIdx.x;
  const float* ps = part + (size_t)ch * 2048;
  const float* pq = part + (size_t)(32 + ch) * 2048;
  redS[tid] = ps[tid]; redQ[tid] = pq[tid];
  __syncthreads();
  for (int off = 128; off; off >>= 1) {
    if (tid < off) { redS[tid] += redS[tid + off]; redQ[tid] += redQ[tid + off]; }
    __syncthreads();
  }
  if (tid == 0) {
    const float mean = redS[0] / cnt;
    const float var = redQ[0] / cnt - mean * mean;
    const float sc = g[ch] * rsqrtf(var + EPSV);
    stats[ch] = sc;
    stats[32 + ch] = bb[ch] - mean * sc;
  }
}

// ---------------------------------------------------------------- K4: conv3 apply + routed MLP fused (8 samples/block, 1 wave)
__global__ __launch_bounds__(64) void conv3_apply_mlp(
    const us* __restrict__ p2g, const us* __restrict__ wt3L,
    const float* __restrict__ cb3, const float* __restrict__ stats3,
    const float* __restrict__ traj,
    const us* __restrict__ ewB, const float* __restrict__ eb,
    const us* __restrict__ owB, const float* __restrict__ ob,
    float* __restrict__ out) {
  __shared__ __align__(16) us p2L[11520];      // [8][36][40]
  __shared__ float h0a[1024];                  // [8][128]
  __shared__ __align__(16) us ht[16 * 136];
  __shared__ float scS[32], shS[32], ebl[384], obl[112];
  const int lane = threadIdx.x, row16 = lane & 15, kg = lane >> 4;
  const int n0 = blockIdx.x * 8, rbase = blockIdx.x * 16;
  for (int i = lane; i < 1152; i += 64) {
    const int s = i / 144, ci = i - s * 144;
    const uint4 v = ((const uint4*)(p2g + (size_t)n0 * 1152))[i];
    *(uint4*)&p2L[(s * 36 + (ci >> 2)) * 40 + (ci & 3) * 8] = v;
  }
  if (lane < 32) { scS[lane] = stats3[lane]; shS[lane] = stats3[32 + lane]; }
  for (int i = lane; i < 384; i += 64) ebl[i] = eb[i];
  for (int i = lane; i < 112; i += 64) obl[i] = (i < 100) ? ob[i] : 0.f;
  __syncthreads();
  const int wA = row16 >> 2, eA = row16 & 3;
  const int inb3 = (2 * (wA >> 1) + (eA >> 1)) * 6 + 2 * (wA & 1) + (eA & 1);
  const float b30 = cb3[row16], b31 = cb3[16 + row16];
  const float sc0 = scS[row16], sh0 = shS[row16];
  const float sc1 = scS[16 + row16], sh1 = shS[16 + row16];
#pragma unroll
  for (int s = 0; s < 8; ++s) {
    f32x4 a0 = {b30, b30, b30, b30};
    f32x4 a1 = {b31, b31, b31, b31};
#pragma unroll
    for (int tap = 0; tap < 9; ++tap) {
      const int ki = tap / 3, kj = tap % 3;
      const s16x8 wf0 = *(const s16x8*)&wt3L[(tap * 32 + row16) * 40 + kg * 8];
      const s16x8 wf1 = *(const s16x8*)&wt3L[(tap * 32 + 16 + row16) * 40 + kg * 8];
      const s16x8 a = *(const s16x8*)&p2L[(s * 36 + inb3 + ki * 6 + kj) * 40 + kg * 8];
      a0 = __builtin_amdgcn_mfma_f32_16x16x32_bf16(a, wf0, a0, 0, 0, 0);
      a1 = __builtin_amdgcn_mfma_f32_16x16x32_bf16(a, wf1, a1, 0, 0, 0);
    }
    float p0 = 0.f, p1v = 0.f;
#pragma unroll
    for (int r = 0; r < 4; ++r) {
      p0 += fmaxf(a0[r] * sc0 + sh0, 0.f);
      p1v += fmaxf(a1[r] * sc1 + sh1, 0.f);
    }
    h0a[s * 128 + row16 * 4 + kg] = p0 * 0.25f;
    h0a[s * 128 + (16 + row16) * 4 + kg] = p1v * 0.25f;
  }
  __syncthreads();
#pragma unroll
  for (int q = 0; q < 4; ++q) {
    const int u = lane + q * 64;
    const int lr = u >> 4, d8 = (u & 15) * 8;
    const float* hp = &h0a[(lr >> 1) * 128 + d8];
    uint4 p;
    p.x = cvtpk(hp[0], hp[1]); p.y = cvtpk(hp[2], hp[3]);
    p.z = cvtpk(hp[4], hp[5]); p.w = cvtpk(hp[6], hp[7]);
    *(uint4*)&ht[lr * 136 + d8] = p;
  }
  float accv[8][4];
#pragma unroll
  for (int ct = 0; ct < 8; ++ct)
#pragma unroll
    for (int r = 0; r < 4; ++r)
      accv[ct][r] = h0a[((kg * 4 + r) >> 1) * 128 + ct * 16 + row16];
  __syncthreads();
  for (int d = 0; d < 3; ++d) {
    int sel[4];
#pragma unroll
    for (int r = 0; r < 4; ++r) {
      const int rowg = rbase + kg * 4 + r;
      const float4 t4 = *(const float4*)(traj + d * 16384 + rowg * 4);
      int s = 0; float mx = t4.x;
      if (t4.y > mx) { mx = t4.y; s = 1; }
      if (t4.z > mx) { mx = t4.z; s = 2; }
      if (t4.w > mx) { mx = t4.w; s = 3; }
      sel[r] = s;
    }
    s16x8 a[4];
#pragma unroll
    for (int kc = 0; kc < 4; ++kc)
      a[kc] = *(const s16x8*)&ht[row16 * 136 + kc * 32 + kg * 8];
    float newacc[8][4];
#pragma unroll
    for (int ct = 0; ct < 8; ++ct)
#pragma unroll
      for (int r = 0; r < 4; ++r)
        newacc[ct][r] = (sel[r] == 3) ? accv[ct][r] : 0.f;
#pragma unroll
    for (int e = 0; e < 3; ++e) {
#pragma unroll
      for (int ct = 0; ct < 8; ++ct) {
        f32x4 t = {0.f, 0.f, 0.f, 0.f};
#pragma unroll
        for (int kc = 0; kc < 4; ++kc) {
          const s16x8 b = *(const s16x8*)&ewB[(e * 128 + ct * 16 + row16) * 128 + kc * 32 + kg * 8];
          t = __builtin_amdgcn_mfma_f32_16x16x32_bf16(a[kc], b, t, 0, 0, 0);
        }
        const float bias = ebl[e * 128 + ct * 16 + row16];
#pragma unroll
        for (int r = 0; r < 4; ++r)
          if (sel[r] == e) newacc[ct][r] = t[r] + bias;
      }
    }
#pragma unroll
    for (int ct = 0; ct < 8; ++ct)
#pragma unroll
      for (int r = 0; r < 4; ++r) {
        float v = newacc[ct][r];
        if (d < 2) v = fmaxf(v, 0.f);
        accv[ct][r] = v;
        ht[(kg * 4 + r) * 136 + ct * 16 + row16] = f2bf1(v);
      }
  }
  s16x8 a[4];
#pragma unroll
  for (int kc = 0; kc < 4; ++kc)
    a[kc] = *(const s16x8*)&ht[row16 * 136 + kc * 32 + kg * 8];
  float preds[7][4];
#pragma unroll
  for (int ct = 0; ct < 7; ++ct) {
    f32x4 t = {0.f, 0.f, 0.f, 0.f};
#pragma unroll
    for (int kc = 0; kc < 4; ++kc) {
      const s16x8 b = *(const s16x8*)&owB[(ct * 16 + row16) * 128 + kc * 32 + kg * 8];
      t = __builtin_amdgcn_mfma_f32_16x16x32_bf16(a[kc], b, t, 0, 0, 0);
    }
    const float bias = obl[ct * 16 + row16];
#pragma unroll
    for (int r = 0; r < 4; ++r) preds[ct][r] = t[r] + bias;
  }
  const bool v6 = (96 + row16) < 100;
#pragma unroll
  for (int r = 0; r < 4; ++r) {
    float mx = -INFINITY;
#pragma unroll
    for (int ct = 0; ct < 7; ++ct)
      if (ct < 6 || v6) mx = fmaxf(mx, preds[ct][r]);
    mx = fmaxf(mx, __shfl_xor(mx, 1)); mx = fmaxf(mx, __shfl_xor(mx, 2));
    mx = fmaxf(mx, __shfl_xor(mx, 4)); mx = fmaxf(mx, __shfl_xor(mx, 8));
    float s = 0.f;
#pragma unroll
    for (int ct = 0; ct < 7; ++ct)
      if (ct < 6 || v6) s += expf(preds[ct][r] - mx);
    s += __shfl_xor(s, 1); s += __shfl_xor(s, 2);
    s += __shfl_xor(s, 4); s += __shfl_xor(s, 8);
    const float lg = mx + logf(s);
    const int rowg = rbase + kg * 4 + r;
#pragma unroll
    for (int ct = 0; ct < 7; ++ct)
      if (ct < 6 || v6) out[(size_t)rowg * 100 + ct * 16 + row16] = preds[ct][r] - lg;
  }
}

// ---------------------------------------------------------------- launch
extern "C" void kernel_launch(void* const* d_in, const int* in_sizes, int n_in,
                              void* d_out, int out_size, void* d_ws, size_t ws_size,
                              hipStream_t stream) {
  const float* x     = (const float*)d_in[0];
  const float* traj  = (const float*)d_in[1];
  const float* score = (const float*)d_in[2];
  const float* cw1 = (const float*)d_in[3];
  const float* cb1 = (const float*)d_in[4];
  const float* g1  = (const float*)d_in[5];
  const float* bb1 = (const float*)d_in[6];
  const float* cw2 = (const float*)d_in[7];
  const float* cb2 = (const float*)d_in[8];
  const float* g2  = (const float*)d_in[9];
  const float* bb2 = (const float*)d_in[10];
  const float* cw3 = (const float*)d_in[11];
  const float* cb3 = (const float*)d_in[12];
  const float* g3  = (const float*)d_in[13];
  const float* bb3 = (const float*)d_in[14];
  const float* eW  = (const float*)d_in[15];
  const float* eb  = (const float*)d_in[16];
  const float* oW  = (const float*)d_in[17];
  const float* ob  = (const float*)d_in[18];
  float* out = (float*)d_out;

  char* ws = (char*)d_ws;
  float* stats1 = (float*)ws;
  float* stats2 = (float*)(ws + 256);
  float* stats3 = (float*)(ws + 512);
  us* wt1n  = (us*)(ws + 1024);
  us* wt2L  = (us*)(ws + 8192);
  us* wt3L  = (us*)(ws + 8192 + 23040);
  us* ewB   = (us*)(ws + 65536);
  us* owB   = (us*)(ws + 65536 + 98304);
  us* y2s   = (us*)(ws + 262144);                // bf16 [2048][36][32][4]
  us* p2g   = (us*)(ws + 262144 + 18874368);     // bf16 [2048][36][32]
  char* pbase = ws + 262144 + 18874368 + 4718592;
  float* part1 = (float*)pbase;
  float* part2 = (float*)(pbase + 524288);
  float* part3 = (float*)(pbase + 1048576);

  prep_weights<<<64, 256, 0, stream>>>(cw1, cw2, cw3, eW, oW, score,
                                       wt1n, wt2L, wt3L, ewB, owB, out + 409600);
  conv1_stats<<<2048, 256, 0, stream>>>(x, wt1n, cb1, part1);
  finalize_stats<<<32, 256, 0, stream>>>(part1, g1, bb1, 2048.f * 900.f, stats1);
  conv1_apply_conv2_stats<<<2048, 256, 0, stream>>>(x, wt1n, cb1, stats1,
                                                    wt2L, cb2, part2, y2s);
  finalize_stats<<<32, 256, 0, stream>>>(part2, g2, bb2, 2048.f * 169.f, stats2);
  bnpool2_conv3_stats<<<256, 256, 0, stream>>>(y2s, stats2, wt3L, cb3, part3, p2g);
  finalize_stats256<<<32, 256, 0, stream>>>(part3, g3, bb3, 2048.f * 16.f, stats3);
  conv3_apply_mlp<<<256, 64, 0, stream>>>(p2g, wt3L, cb3, stats3, traj,
                                          ewB, eb, owB, ob, out);
}